// Round 1
// baseline (4930.489 us; speedup 1.0000x reference)
//
#include <hip/hip_runtime.h>

#define N_CAPS 219024   // 117*117*16
#define J_CAPS 8

// ---------------- conv1: [2,250,250,3] x [9,9,3,256] s1 VALID -> relu -> [2,242,242,256]
__global__ __launch_bounds__(256) void conv1_kernel(
    const float* __restrict__ in, const float* __restrict__ w,
    const float* __restrict__ bias, float* __restrict__ out)
{
    // grid: (16, 242, 2); block 256 threads = one out-channel each; 16 ox positions per block
    const int oc  = threadIdx.x;
    const int ox0 = blockIdx.x * 16;
    const int oy  = blockIdx.y;
    const int b   = blockIdx.z;

    __shared__ float lin[9][24][3];   // input patch: rows oy..oy+8, cols ox0..ox0+23
    for (int idx = threadIdx.x; idx < 9 * 24 * 3; idx += 256) {
        int r   = idx / (24 * 3);
        int rem = idx - r * (24 * 3);
        int col = rem / 3;
        int c   = rem - col * 3;
        int iy  = oy + r;
        int ix  = ox0 + col;
        float v = 0.f;
        if (ix < 250) v = in[((b * 250 + iy) * 250 + ix) * 3 + c];
        lin[r][col][c] = v;
    }
    __syncthreads();

    float acc[16];
#pragma unroll
    for (int t = 0; t < 16; ++t) acc[t] = 0.f;

    for (int ky = 0; ky < 9; ++ky) {
#pragma unroll
        for (int ic = 0; ic < 3; ++ic) {
            float xv[24];
#pragma unroll
            for (int c2 = 0; c2 < 24; ++c2) xv[c2] = lin[ky][c2][ic];
#pragma unroll
            for (int kx = 0; kx < 9; ++kx) {
                float wv = w[((ky * 9 + kx) * 3 + ic) * 256 + oc];
#pragma unroll
                for (int t = 0; t < 16; ++t)
                    acc[t] += xv[kx + t] * wv;
            }
        }
    }

    float bv = bias[oc];
#pragma unroll
    for (int t = 0; t < 16; ++t) {
        int ox = ox0 + t;
        if (ox < 242) {
            float v = acc[t] + bv;
            out[((b * 242 + oy) * 242 + ox) * 256 + oc] = v > 0.f ? v : 0.f;
        }
    }
}

// ---------------- conv2: [2,242,242,256] x [9,9,256,128] s2 VALID -> [2,117,117,128] (+bias, linear)
__global__ __launch_bounds__(256) void conv2_kernel(
    const float* __restrict__ x, const float* __restrict__ w,
    const float* __restrict__ bias, float* __restrict__ out)
{
    // grid: (8, 117, 2); block 256: oc = tid&127, half = tid>>7; 16 ox per block (8 per half)
    const int oc   = threadIdx.x & 127;
    const int half = threadIdx.x >> 7;
    const int ox0  = blockIdx.x * 16;
    const int oy   = blockIdx.y;
    const int b    = blockIdx.z;

    __shared__ float row[39 * 256];   // one input row: 39 cols x 256 ic = 39936 B

    float acc[8];
#pragma unroll
    for (int t = 0; t < 8; ++t) acc[t] = 0.f;

    for (int ky = 0; ky < 9; ++ky) {
        int iy = 2 * oy + ky;          // <= 240, always valid
        __syncthreads();
        for (int idx = threadIdx.x; idx < 39 * 256; idx += 256) {
            int col = idx >> 8;
            int ic  = idx & 255;
            int ix  = 2 * ox0 + col;
            row[idx] = (ix < 242) ? x[((b * 242 + iy) * 242 + ix) * 256 + ic] : 0.f;
        }
        __syncthreads();

        const float* wk = w + (ky * 9) * 256 * 128 + oc;
        for (int ic = 0; ic < 256; ++ic) {
            float xv[24];
#pragma unroll
            for (int c = 0; c < 24; ++c)
                xv[c] = row[(16 * half + c) * 256 + ic];
#pragma unroll
            for (int kx = 0; kx < 9; ++kx) {
                float wv = wk[(kx * 256 + ic) * 128];
#pragma unroll
                for (int tt = 0; tt < 8; ++tt)
                    acc[tt] += xv[2 * tt + kx] * wv;
            }
        }
    }

    float bv = bias[oc];
#pragma unroll
    for (int tt = 0; tt < 8; ++tt) {
        int ox = ox0 + half * 8 + tt;
        if (ox < 117)
            out[((b * 117 + oy) * 117 + ox) * 128 + oc] = acc[tt] + bv;
    }
}

// ---------------- squash over groups of 8 (in-place safe: each thread owns its 8 floats)
__global__ __launch_bounds__(256) void squash_u_kernel(float* data, int n_groups)
{
    int i = blockIdx.x * 256 + threadIdx.x;
    if (i >= n_groups) return;
    float4* p = (float4*)(data + (size_t)i * 8);
    float4 a = p[0], c = p[1];
    float sq = a.x * a.x + a.y * a.y + a.z * a.z + a.w * a.w
             + c.x * c.x + c.y * c.y + c.z * c.z + c.w * c.w;
    float scale = (sq / (1.f + sq)) * rsqrtf(sq + 1e-7f);
    p[0] = make_float4(a.x * scale, a.y * scale, a.z * scale, a.w * scale);
    p[1] = make_float4(c.x * scale, c.y * scale, c.z * scale, c.w * scale);
}

// ---------------- u_hat[b,j,i,o] = sum_d W[j,i,o,d] * u[b,i,d]
__global__ __launch_bounds__(256) void uhat_kernel(
    const float* __restrict__ W, const float* __restrict__ u,
    float* __restrict__ uhat)
{
    int idx = blockIdx.x * 256 + threadIdx.x;   // idx = j*N + i  (< 1,752,192)
    if (idx >= J_CAPS * N_CAPS) return;
    int j = idx / N_CAPS;
    int i = idx - j * N_CAPS;

    const float4* wp = (const float4*)(W + (size_t)idx * 64);
    const float4* u0 = (const float4*)(u + (size_t)i * 8);
    const float4* u1 = (const float4*)(u + ((size_t)N_CAPS + i) * 8);
    float4 u0a = u0[0], u0b = u0[1];
    float4 u1a = u1[0], u1b = u1[1];

    float o0[8], o1[8];
#pragma unroll
    for (int o = 0; o < 8; ++o) {
        float4 wa = wp[2 * o], wb = wp[2 * o + 1];
        o0[o] = wa.x * u0a.x + wa.y * u0a.y + wa.z * u0a.z + wa.w * u0a.w
              + wb.x * u0b.x + wb.y * u0b.y + wb.z * u0b.z + wb.w * u0b.w;
        o1[o] = wa.x * u1a.x + wa.y * u1a.y + wa.z * u1a.z + wa.w * u1a.w
              + wb.x * u1b.x + wb.y * u1b.y + wb.z * u1b.z + wb.w * u1b.w;
    }
    float4* d0 = (float4*)(uhat + ((size_t)(0 * J_CAPS + j) * N_CAPS + i) * 8);
    float4* d1 = (float4*)(uhat + ((size_t)(1 * J_CAPS + j) * N_CAPS + i) * 8);
    d0[0] = make_float4(o0[0], o0[1], o0[2], o0[3]);
    d0[1] = make_float4(o0[4], o0[5], o0[6], o0[7]);
    d1[0] = make_float4(o1[0], o1[1], o1[2], o1[3]);
    d1[1] = make_float4(o1[4], o1[5], o1[6], o1[7]);
}

// ---------------- fused routing iteration:
// MODE 0: c = 1/8 (b_logits == 0), no v needed
// MODE 1: b = dot(v_prev, u_hat), write b_out, c = softmax_j(b)
// MODE 2: b = b_in + dot(v_prev, u_hat), c = softmax_j(b)
// accumulates s[b,j,o] via register acc -> wave shuffle -> LDS -> global atomics
template <int MODE>
__global__ __launch_bounds__(256) void routing_kernel(
    const float* __restrict__ uhat, const float* __restrict__ vprev,
    const float* __restrict__ b_in, float* __restrict__ b_out,
    float* __restrict__ s)
{
    const int bb = blockIdx.y;
    __shared__ float vsh[64];
    __shared__ float ssh[64];
    if (threadIdx.x < 64) {
        ssh[threadIdx.x] = 0.f;
        vsh[threadIdx.x] = (MODE > 0) ? vprev[bb * 64 + threadIdx.x] : 0.f;
    }
    __syncthreads();

    float acc[64];
#pragma unroll
    for (int k = 0; k < 64; ++k) acc[k] = 0.f;

    const float* ub = uhat + (size_t)bb * J_CAPS * (size_t)N_CAPS * 8;
    for (int i = blockIdx.x * 256 + threadIdx.x; i < N_CAPS; i += gridDim.x * 256) {
        float uh[64];
#pragma unroll
        for (int j = 0; j < 8; ++j) {
            const float* p = ub + ((size_t)j * N_CAPS + i) * 8;
            float4 x0 = *(const float4*)p;
            float4 x1 = *(const float4*)(p + 4);
            uh[j * 8 + 0] = x0.x; uh[j * 8 + 1] = x0.y;
            uh[j * 8 + 2] = x0.z; uh[j * 8 + 3] = x0.w;
            uh[j * 8 + 4] = x1.x; uh[j * 8 + 5] = x1.y;
            uh[j * 8 + 6] = x1.z; uh[j * 8 + 7] = x1.w;
        }
        float c[8];
        if (MODE == 0) {
#pragma unroll
            for (int j = 0; j < 8; ++j) c[j] = 0.125f;
        } else {
            float bj[8];
#pragma unroll
            for (int j = 0; j < 8; ++j) {
                float d = 0.f;
#pragma unroll
                for (int o = 0; o < 8; ++o) d += vsh[j * 8 + o] * uh[j * 8 + o];
                bj[j] = d;
            }
            if (MODE == 2) {
#pragma unroll
                for (int j = 0; j < 8; ++j)
                    bj[j] += b_in[((size_t)bb * 8 + j) * N_CAPS + i];
            } else {
#pragma unroll
                for (int j = 0; j < 8; ++j)
                    b_out[((size_t)bb * 8 + j) * N_CAPS + i] = bj[j];
            }
            float m = bj[0];
#pragma unroll
            for (int j = 1; j < 8; ++j) m = fmaxf(m, bj[j]);
            float se = 0.f;
#pragma unroll
            for (int j = 0; j < 8; ++j) { c[j] = __expf(bj[j] - m); se += c[j]; }
            float inv = 1.f / se;
#pragma unroll
            for (int j = 0; j < 8; ++j) c[j] *= inv;
        }
#pragma unroll
        for (int k = 0; k < 64; ++k) acc[k] += c[k >> 3] * uh[k];
    }

    // reduce: wave shuffle -> lane0 LDS atomic -> block -> global atomic
#pragma unroll
    for (int k = 0; k < 64; ++k) {
        float v = acc[k];
        for (int off = 32; off > 0; off >>= 1)
            v += __shfl_down(v, off, 64);
        if ((threadIdx.x & 63) == 0) atomicAdd(&ssh[k], v);
    }
    __syncthreads();
    if (threadIdx.x < 64) atomicAdd(&s[bb * 64 + threadIdx.x], ssh[threadIdx.x]);
}

// ---------------- squash of s -> v  (16 (b,j) rows of 8)
__global__ void squash_v_kernel(const float* __restrict__ s, float* __restrict__ v)
{
    int t = threadIdx.x;
    if (t >= 16) return;
    const float4* p = (const float4*)(s + t * 8);
    float4 a = p[0], c = p[1];
    float sq = a.x * a.x + a.y * a.y + a.z * a.z + a.w * a.w
             + c.x * c.x + c.y * c.y + c.z * c.z + c.w * c.w;
    float scale = (sq / (1.f + sq)) * rsqrtf(sq + 1e-7f);
    float4* d = (float4*)(v + t * 8);
    d[0] = make_float4(a.x * scale, a.y * scale, a.z * scale, a.w * scale);
    d[1] = make_float4(c.x * scale, c.y * scale, c.z * scale, c.w * scale);
}

__global__ void zero_kernel(float* p, int n)
{
    int i = blockIdx.x * 256 + threadIdx.x;
    if (i < n) p[i] = 0.f;
}

extern "C" void kernel_launch(void* const* d_in, const int* in_sizes, int n_in,
                              void* d_out, int out_size, void* d_ws, size_t ws_size,
                              hipStream_t stream)
{
    const float* in = (const float*)d_in[0];
    const float* w1 = (const float*)d_in[1];
    const float* b1 = (const float*)d_in[2];
    const float* w2 = (const float*)d_in[3];
    const float* b2 = (const float*)d_in[4];
    const float* Wc = (const float*)d_in[5];
    float* out = (float*)d_out;
    float* ws  = (float*)d_ws;

    // workspace layout (floats):
    //  region A [0, 29984768): x1 (2*242*242*256); later reused for u_hat (28035072)
    //  region B [29984768, +3504384): pc -> u (in-place squash)
    //  region C [33489152, +3504384): b_logits
    //  sbuf at 36993536 (128), vbuf at 36993664 (128)   total ~148 MB
    float* x1   = ws;
    float* pc   = ws + 29984768;
    float* blog = ws + 33489152;
    float* sbuf = ws + 36993536;
    float* vbuf = ws + 36993664;
    float* uhat = ws;   // aliases x1 (dead after conv2)

    conv1_kernel<<<dim3(16, 242, 2), 256, 0, stream>>>(in, w1, b1, x1);
    conv2_kernel<<<dim3(8, 117, 2), 256, 0, stream>>>(x1, w2, b2, pc);
    squash_u_kernel<<<(2 * N_CAPS + 255) / 256, 256, 0, stream>>>(pc, 2 * N_CAPS);
    uhat_kernel<<<(J_CAPS * N_CAPS + 255) / 256, 256, 0, stream>>>(Wc, pc, uhat);

    zero_kernel<<<1, 128, 0, stream>>>(sbuf, 128);
    routing_kernel<0><<<dim3(256, 2), 256, 0, stream>>>(uhat, nullptr, nullptr, nullptr, sbuf);
    squash_v_kernel<<<1, 64, 0, stream>>>(sbuf, vbuf);

    zero_kernel<<<1, 128, 0, stream>>>(sbuf, 128);
    routing_kernel<1><<<dim3(256, 2), 256, 0, stream>>>(uhat, vbuf, nullptr, blog, sbuf);
    squash_v_kernel<<<1, 64, 0, stream>>>(sbuf, vbuf);

    zero_kernel<<<1, 128, 0, stream>>>(sbuf, 128);
    routing_kernel<2><<<dim3(256, 2), 256, 0, stream>>>(uhat, vbuf, blog, nullptr, sbuf);
    squash_v_kernel<<<1, 64, 0, stream>>>(sbuf, out);
}

// Round 2
// 1515.686 us; speedup vs baseline: 3.2530x; 3.2530x over previous
//
#include <hip/hip_runtime.h>

#define N_CAPS 219024   // 117*117*16
#define J_CAPS 8

typedef __attribute__((ext_vector_type(8))) __bf16 bf16x8;
typedef __attribute__((ext_vector_type(4))) float  f32x4;
typedef __attribute__((ext_vector_type(8))) short  short8;

__device__ __forceinline__ unsigned short f2bf(float f) {
    unsigned int u = __float_as_uint(f);
    u = (u + 0x7FFFu + ((u >> 16) & 1u)) >> 16;   // RNE
    return (unsigned short)u;
}

// ---------------- conv1: [2,250,250,3] x [9,9,3,256] s1 VALID -> relu -> bf16 [2,242,242,256]
__global__ __launch_bounds__(256) void conv1_kernel(
    const float* __restrict__ in, const float* __restrict__ w,
    const float* __restrict__ bias, unsigned short* __restrict__ out)
{
    const int oc  = threadIdx.x;
    const int ox0 = blockIdx.x * 16;
    const int oy  = blockIdx.y;
    const int b   = blockIdx.z;

    __shared__ float lin[9][24][3];
    for (int idx = threadIdx.x; idx < 9 * 24 * 3; idx += 256) {
        int r   = idx / (24 * 3);
        int rem = idx - r * (24 * 3);
        int col = rem / 3;
        int c   = rem - col * 3;
        int iy  = oy + r;
        int ix  = ox0 + col;
        float v = 0.f;
        if (ix < 250) v = in[((b * 250 + iy) * 250 + ix) * 3 + c];
        lin[r][col][c] = v;
    }
    __syncthreads();

    float acc[16];
#pragma unroll
    for (int t = 0; t < 16; ++t) acc[t] = 0.f;

    for (int ky = 0; ky < 9; ++ky) {
#pragma unroll
        for (int ic = 0; ic < 3; ++ic) {
            float xv[24];
#pragma unroll
            for (int c2 = 0; c2 < 24; ++c2) xv[c2] = lin[ky][c2][ic];
#pragma unroll
            for (int kx = 0; kx < 9; ++kx) {
                float wv = w[((ky * 9 + kx) * 3 + ic) * 256 + oc];
#pragma unroll
                for (int t = 0; t < 16; ++t)
                    acc[t] += xv[kx + t] * wv;
            }
        }
    }

    float bv = bias[oc];
#pragma unroll
    for (int t = 0; t < 16; ++t) {
        int ox = ox0 + t;
        if (ox < 242) {
            float v = acc[t] + bv;
            out[((b * 242 + oy) * 242 + ox) * 256 + oc] = f2bf(v > 0.f ? v : 0.f);
        }
    }
}

// ---------------- w2 [9,9,256,128] fp32 -> w2t [81,128,256] bf16 (p, oc, ic)
__global__ __launch_bounds__(256) void w2_convert_kernel(
    const float* __restrict__ w, unsigned short* __restrict__ wt)
{
    int idx = blockIdx.x * 256 + threadIdx.x;     // output-ordered: ((p*128+oc)*256+ic)
    if (idx >= 81 * 128 * 256) return;
    int ic = idx & 255;
    int t  = idx >> 8;
    int oc = t & 127;
    int p  = t >> 7;
    wt[idx] = f2bf(w[(p * 256 + ic) * 128 + oc]);
}

// ---------------- conv2 as implicit GEMM, bf16 MFMA 16x16x32
// out[b,oy,ox,oc] = sum_{ky,kx,ic} x[b,2oy+ky,2ox+kx,ic] * w[ky,kx,ic,oc] + bias
// block: 64 M(ox) x 128 N(oc); 4 waves, wave tile 32M x 64N (2x4 16x16 tiles)
// LDS: A row (135 cols x 64-ic quarter) + B tile (128 oc x 64-ic quarter), XOR-swizzled
__global__ __launch_bounds__(256) void conv2_mfma_kernel(
    const unsigned short* __restrict__ x1bf,   // [2,242,242,256] bf16
    const unsigned short* __restrict__ w2t,    // [81,128,256] bf16
    const float* __restrict__ bias,
    float* __restrict__ out)                   // [2,117,117,128] fp32
{
    const int bx   = blockIdx.x;               // 0,1: ox tile of 64
    const int oy   = blockIdx.y;
    const int b    = blockIdx.z;
    const int tid  = threadIdx.x;
    const int wave = tid >> 6;
    const int lane = tid & 63;
    const int li   = lane & 15;
    const int quad = lane >> 4;
    const int wm   = (wave & 1) * 32;
    const int wn   = (wave >> 1) * 64;
    const int ox0  = bx * 64;

    __shared__ __align__(16) unsigned short As[135 * 64];  // [c][k-quarter] swizzled
    __shared__ __align__(16) unsigned short Bs[128 * 64];  // [n][k-quarter] swizzled

    f32x4 acc[2][4];
#pragma unroll
    for (int mt = 0; mt < 2; ++mt)
#pragma unroll
        for (int nt = 0; nt < 4; ++nt)
            acc[mt][nt] = (f32x4){0.f, 0.f, 0.f, 0.f};

    for (int ky = 0; ky < 9; ++ky) {
        const int iy = 2 * oy + ky;                       // always < 242
        const unsigned short* xrow = x1bf + ((size_t)(b * 242 + iy) * 242) * 256;
        for (int hq = 0; hq < 4; ++hq) {                  // ic quarter
            __syncthreads();                              // prior readers of As done
            // stage A: 135 cols x 8 chunks of 8 bf16
            for (int idx = tid; idx < 135 * 8; idx += 256) {
                int c    = idx >> 3;
                int kkc  = idx & 7;
                int gcol = 2 * ox0 + c;
                short8 v = {0, 0, 0, 0, 0, 0, 0, 0};
                if (gcol < 242)
                    v = *(const short8*)&xrow[(size_t)gcol * 256 + hq * 64 + kkc * 8];
                *(short8*)&As[c * 64 + ((kkc ^ ((c >> 1) & 7)) * 8)] = v;
            }
            for (int kx = 0; kx < 9; ++kx) {
                __syncthreads();                          // prior Bs readers done; As visible
                const unsigned short* wp = w2t + (size_t)(ky * 9 + kx) * 128 * 256;
                for (int idx = tid; idx < 128 * 8; idx += 256) {
                    int n   = idx >> 3;
                    int kkc = idx & 7;
                    *(short8*)&Bs[n * 64 + ((kkc ^ (n & 7)) * 8)] =
                        *(const short8*)&wp[(size_t)n * 256 + hq * 64 + kkc * 8];
                }
                __syncthreads();
#pragma unroll
                for (int kh = 0; kh < 2; ++kh) {          // kc = kh*32
                    const int ch = kh * 4 + quad;         // k-chunk index within quarter
                    const int c0 = 2 * (wm + li) + kx;
                    const int c1 = 2 * (wm + 16 + li) + kx;
                    bf16x8 a0 = *(const bf16x8*)&As[c0 * 64 + ((ch ^ ((c0 >> 1) & 7)) * 8)];
                    bf16x8 a1 = *(const bf16x8*)&As[c1 * 64 + ((ch ^ ((c1 >> 1) & 7)) * 8)];
                    const int n0 = wn + li;
                    const int n1 = wn + 16 + li;
                    const int n2 = wn + 32 + li;
                    const int n3 = wn + 48 + li;
                    bf16x8 b0 = *(const bf16x8*)&Bs[n0 * 64 + ((ch ^ (n0 & 7)) * 8)];
                    bf16x8 b1 = *(const bf16x8*)&Bs[n1 * 64 + ((ch ^ (n1 & 7)) * 8)];
                    bf16x8 b2 = *(const bf16x8*)&Bs[n2 * 64 + ((ch ^ (n2 & 7)) * 8)];
                    bf16x8 b3 = *(const bf16x8*)&Bs[n3 * 64 + ((ch ^ (n3 & 7)) * 8)];
                    acc[0][0] = __builtin_amdgcn_mfma_f32_16x16x32_bf16(a0, b0, acc[0][0], 0, 0, 0);
                    acc[0][1] = __builtin_amdgcn_mfma_f32_16x16x32_bf16(a0, b1, acc[0][1], 0, 0, 0);
                    acc[0][2] = __builtin_amdgcn_mfma_f32_16x16x32_bf16(a0, b2, acc[0][2], 0, 0, 0);
                    acc[0][3] = __builtin_amdgcn_mfma_f32_16x16x32_bf16(a0, b3, acc[0][3], 0, 0, 0);
                    acc[1][0] = __builtin_amdgcn_mfma_f32_16x16x32_bf16(a1, b0, acc[1][0], 0, 0, 0);
                    acc[1][1] = __builtin_amdgcn_mfma_f32_16x16x32_bf16(a1, b1, acc[1][1], 0, 0, 0);
                    acc[1][2] = __builtin_amdgcn_mfma_f32_16x16x32_bf16(a1, b2, acc[1][2], 0, 0, 0);
                    acc[1][3] = __builtin_amdgcn_mfma_f32_16x16x32_bf16(a1, b3, acc[1][3], 0, 0, 0);
                }
            }
        }
    }

    // epilogue: C/D layout col=lane&15, row=quad*4+reg
#pragma unroll
    for (int mt = 0; mt < 2; ++mt) {
#pragma unroll
        for (int nt = 0; nt < 4; ++nt) {
            const int oc = wn + nt * 16 + li;
            const float bv = bias[oc];
#pragma unroll
            for (int r = 0; r < 4; ++r) {
                const int m  = wm + mt * 16 + quad * 4 + r;
                const int ox = ox0 + m;
                if (ox < 117)
                    out[((size_t)(b * 117 + oy) * 117 + ox) * 128 + oc] = acc[mt][nt][r] + bv;
            }
        }
    }
}

// ---------------- squash over groups of 8 (in-place)
__global__ __launch_bounds__(256) void squash_u_kernel(float* data, int n_groups)
{
    int i = blockIdx.x * 256 + threadIdx.x;
    if (i >= n_groups) return;
    float4* p = (float4*)(data + (size_t)i * 8);
    float4 a = p[0], c = p[1];
    float sq = a.x * a.x + a.y * a.y + a.z * a.z + a.w * a.w
             + c.x * c.x + c.y * c.y + c.z * c.z + c.w * c.w;
    float scale = (sq / (1.f + sq)) * rsqrtf(sq + 1e-7f);
    p[0] = make_float4(a.x * scale, a.y * scale, a.z * scale, a.w * scale);
    p[1] = make_float4(c.x * scale, c.y * scale, c.z * scale, c.w * scale);
}

// ---------------- u_hat[b,j,i,o] = sum_d W[j,i,o,d] * u[b,i,d]
__global__ __launch_bounds__(256) void uhat_kernel(
    const float* __restrict__ W, const float* __restrict__ u,
    float* __restrict__ uhat)
{
    int idx = blockIdx.x * 256 + threadIdx.x;   // idx = j*N + i
    if (idx >= J_CAPS * N_CAPS) return;
    int j = idx / N_CAPS;
    int i = idx - j * N_CAPS;

    const float4* wp = (const float4*)(W + (size_t)idx * 64);
    const float4* u0 = (const float4*)(u + (size_t)i * 8);
    const float4* u1 = (const float4*)(u + ((size_t)N_CAPS + i) * 8);
    float4 u0a = u0[0], u0b = u0[1];
    float4 u1a = u1[0], u1b = u1[1];

    float o0[8], o1[8];
#pragma unroll
    for (int o = 0; o < 8; ++o) {
        float4 wa = wp[2 * o], wb = wp[2 * o + 1];
        o0[o] = wa.x * u0a.x + wa.y * u0a.y + wa.z * u0a.z + wa.w * u0a.w
              + wb.x * u0b.x + wb.y * u0b.y + wb.z * u0b.z + wb.w * u0b.w;
        o1[o] = wa.x * u1a.x + wa.y * u1a.y + wa.z * u1a.z + wa.w * u1a.w
              + wb.x * u1b.x + wb.y * u1b.y + wb.z * u1b.z + wb.w * u1b.w;
    }
    float4* d0 = (float4*)(uhat + ((size_t)(0 * J_CAPS + j) * N_CAPS + i) * 8);
    float4* d1 = (float4*)(uhat + ((size_t)(1 * J_CAPS + j) * N_CAPS + i) * 8);
    d0[0] = make_float4(o0[0], o0[1], o0[2], o0[3]);
    d0[1] = make_float4(o0[4], o0[5], o0[6], o0[7]);
    d1[0] = make_float4(o1[0], o1[1], o1[2], o1[3]);
    d1[1] = make_float4(o1[4], o1[5], o1[6], o1[7]);
}

// ---------------- fused routing iteration (MODE 0/1/2 as before)
template <int MODE>
__global__ __launch_bounds__(256) void routing_kernel(
    const float* __restrict__ uhat, const float* __restrict__ vprev,
    const float* __restrict__ b_in, float* __restrict__ b_out,
    float* __restrict__ s)
{
    const int bb = blockIdx.y;
    __shared__ float vsh[64];
    __shared__ float ssh[64];
    if (threadIdx.x < 64) {
        ssh[threadIdx.x] = 0.f;
        vsh[threadIdx.x] = (MODE > 0) ? vprev[bb * 64 + threadIdx.x] : 0.f;
    }
    __syncthreads();

    float acc[64];
#pragma unroll
    for (int k = 0; k < 64; ++k) acc[k] = 0.f;

    const float* ub = uhat + (size_t)bb * J_CAPS * (size_t)N_CAPS * 8;
    for (int i = blockIdx.x * 256 + threadIdx.x; i < N_CAPS; i += gridDim.x * 256) {
        float uh[64];
#pragma unroll
        for (int j = 0; j < 8; ++j) {
            const float* p = ub + ((size_t)j * N_CAPS + i) * 8;
            float4 x0 = *(const float4*)p;
            float4 x1 = *(const float4*)(p + 4);
            uh[j * 8 + 0] = x0.x; uh[j * 8 + 1] = x0.y;
            uh[j * 8 + 2] = x0.z; uh[j * 8 + 3] = x0.w;
            uh[j * 8 + 4] = x1.x; uh[j * 8 + 5] = x1.y;
            uh[j * 8 + 6] = x1.z; uh[j * 8 + 7] = x1.w;
        }
        float c[8];
        if (MODE == 0) {
#pragma unroll
            for (int j = 0; j < 8; ++j) c[j] = 0.125f;
        } else {
            float bj[8];
#pragma unroll
            for (int j = 0; j < 8; ++j) {
                float d = 0.f;
#pragma unroll
                for (int o = 0; o < 8; ++o) d += vsh[j * 8 + o] * uh[j * 8 + o];
                bj[j] = d;
            }
            if (MODE == 2) {
#pragma unroll
                for (int j = 0; j < 8; ++j)
                    bj[j] += b_in[((size_t)bb * 8 + j) * N_CAPS + i];
            } else {
#pragma unroll
                for (int j = 0; j < 8; ++j)
                    b_out[((size_t)bb * 8 + j) * N_CAPS + i] = bj[j];
            }
            float m = bj[0];
#pragma unroll
            for (int j = 1; j < 8; ++j) m = fmaxf(m, bj[j]);
            float se = 0.f;
#pragma unroll
            for (int j = 0; j < 8; ++j) { c[j] = __expf(bj[j] - m); se += c[j]; }
            float inv = 1.f / se;
#pragma unroll
            for (int j = 0; j < 8; ++j) c[j] *= inv;
        }
#pragma unroll
        for (int k = 0; k < 64; ++k) acc[k] += c[k >> 3] * uh[k];
    }

#pragma unroll
    for (int k = 0; k < 64; ++k) {
        float v = acc[k];
        for (int off = 32; off > 0; off >>= 1)
            v += __shfl_down(v, off, 64);
        if ((threadIdx.x & 63) == 0) atomicAdd(&ssh[k], v);
    }
    __syncthreads();
    if (threadIdx.x < 64) atomicAdd(&s[bb * 64 + threadIdx.x], ssh[threadIdx.x]);
}

// ---------------- squash of s -> v
__global__ void squash_v_kernel(const float* __restrict__ s, float* __restrict__ v)
{
    int t = threadIdx.x;
    if (t >= 16) return;
    const float4* p = (const float4*)(s + t * 8);
    float4 a = p[0], c = p[1];
    float sq = a.x * a.x + a.y * a.y + a.z * a.z + a.w * a.w
             + c.x * c.x + c.y * c.y + c.z * c.z + c.w * c.w;
    float scale = (sq / (1.f + sq)) * rsqrtf(sq + 1e-7f);
    float4* d = (float4*)(v + t * 8);
    d[0] = make_float4(a.x * scale, a.y * scale, a.z * scale, a.w * scale);
    d[1] = make_float4(c.x * scale, c.y * scale, c.z * scale, c.w * scale);
}

__global__ void zero_kernel(float* p, int n)
{
    int i = blockIdx.x * 256 + threadIdx.x;
    if (i < n) p[i] = 0.f;
}

extern "C" void kernel_launch(void* const* d_in, const int* in_sizes, int n_in,
                              void* d_out, int out_size, void* d_ws, size_t ws_size,
                              hipStream_t stream)
{
    const float* in = (const float*)d_in[0];
    const float* w1 = (const float*)d_in[1];
    const float* b1 = (const float*)d_in[2];
    const float* w2 = (const float*)d_in[3];
    const float* b2 = (const float*)d_in[4];
    const float* Wc = (const float*)d_in[5];
    float* out = (float*)d_out;
    char* wsb  = (char*)d_ws;

    // workspace layout (bytes):
    //  [0, 112,140,288):  uhat fp32 [2,8,219024,8]; aliased by x1bf bf16 (59,969,536 B, dead before uhat)
    //  [112,140,288):     pc fp32  (14,017,536 B)
    //  [126,157,824):     blog fp32 (14,017,536 B)
    //  [140,175,360):     w2t bf16 (5,308,416 B)
    //  [145,483,776):     sbuf (512 B); [145,484,288): vbuf (512 B)   total ~145.5 MB
    float*          uhat = (float*)wsb;
    unsigned short* x1bf = (unsigned short*)wsb;
    float*          pc   = (float*)(wsb + 112140288);
    float*          blog = (float*)(wsb + 126157824);
    unsigned short* w2t  = (unsigned short*)(wsb + 140175360);
    float*          sbuf = (float*)(wsb + 145483776);
    float*          vbuf = (float*)(wsb + 145484288);

    w2_convert_kernel<<<(81 * 128 * 256 + 255) / 256, 256, 0, stream>>>(w2, w2t);
    conv1_kernel<<<dim3(16, 242, 2), 256, 0, stream>>>(in, w1, b1, x1bf);
    conv2_mfma_kernel<<<dim3(2, 117, 2), 256, 0, stream>>>(x1bf, w2t, b2, pc);
    squash_u_kernel<<<(2 * N_CAPS + 255) / 256, 256, 0, stream>>>(pc, 2 * N_CAPS);
    uhat_kernel<<<(J_CAPS * N_CAPS + 255) / 256, 256, 0, stream>>>(Wc, pc, uhat);

    zero_kernel<<<1, 128, 0, stream>>>(sbuf, 128);
    routing_kernel<0><<<dim3(256, 2), 256, 0, stream>>>(uhat, nullptr, nullptr, nullptr, sbuf);
    squash_v_kernel<<<1, 64, 0, stream>>>(sbuf, vbuf);

    zero_kernel<<<1, 128, 0, stream>>>(sbuf, 128);
    routing_kernel<1><<<dim3(256, 2), 256, 0, stream>>>(uhat, vbuf, nullptr, blog, sbuf);
    squash_v_kernel<<<1, 64, 0, stream>>>(sbuf, vbuf);

    zero_kernel<<<1, 128, 0, stream>>>(sbuf, 128);
    routing_kernel<2><<<dim3(256, 2), 256, 0, stream>>>(uhat, vbuf, blog, nullptr, sbuf);
    squash_v_kernel<<<1, 64, 0, stream>>>(sbuf, out);
}

// Round 3
// 1313.153 us; speedup vs baseline: 3.7547x; 1.1542x over previous
//
#include <hip/hip_runtime.h>

#define N_CAPS 219024   // 117*117*16
#define J_CAPS 8

typedef __attribute__((ext_vector_type(8))) __bf16 bf16x8;
typedef __attribute__((ext_vector_type(4))) float  f32x4;
typedef __attribute__((ext_vector_type(8))) short  short8;

__device__ __forceinline__ unsigned short f2bf(float f) {
    unsigned int u = __float_as_uint(f);
    u = (u + 0x7FFFu + ((u >> 16) & 1u)) >> 16;   // RNE
    return (unsigned short)u;
}

// ---------------- conv1: [2,250,250,3] x [9,9,3,256] s1 VALID -> relu -> bf16 [2,242,242,256]
__global__ __launch_bounds__(256) void conv1_kernel(
    const float* __restrict__ in, const float* __restrict__ w,
    const float* __restrict__ bias, unsigned short* __restrict__ out)
{
    const int oc  = threadIdx.x;
    const int ox0 = blockIdx.x * 16;
    const int oy  = blockIdx.y;
    const int b   = blockIdx.z;

    __shared__ float lin[9][24][3];
    for (int idx = threadIdx.x; idx < 9 * 24 * 3; idx += 256) {
        int r   = idx / (24 * 3);
        int rem = idx - r * (24 * 3);
        int col = rem / 3;
        int c   = rem - col * 3;
        int iy  = oy + r;
        int ix  = ox0 + col;
        float v = 0.f;
        if (ix < 250) v = in[((b * 250 + iy) * 250 + ix) * 3 + c];
        lin[r][col][c] = v;
    }
    __syncthreads();

    float acc[16];
#pragma unroll
    for (int t = 0; t < 16; ++t) acc[t] = 0.f;

    for (int ky = 0; ky < 9; ++ky) {
#pragma unroll
        for (int ic = 0; ic < 3; ++ic) {
            float xv[24];
#pragma unroll
            for (int c2 = 0; c2 < 24; ++c2) xv[c2] = lin[ky][c2][ic];
#pragma unroll
            for (int kx = 0; kx < 9; ++kx) {
                float wv = w[((ky * 9 + kx) * 3 + ic) * 256 + oc];
#pragma unroll
                for (int t = 0; t < 16; ++t)
                    acc[t] += xv[kx + t] * wv;
            }
        }
    }

    float bv = bias[oc];
#pragma unroll
    for (int t = 0; t < 16; ++t) {
        int ox = ox0 + t;
        if (ox < 242) {
            float v = acc[t] + bv;
            out[((b * 242 + oy) * 242 + ox) * 256 + oc] = f2bf(v > 0.f ? v : 0.f);
        }
    }
}

// ---------------- w2 [9,9,256,128] fp32 -> w2t [81,128,256] bf16 (p, oc, ic)
__global__ __launch_bounds__(256) void w2_convert_kernel(
    const float* __restrict__ w, unsigned short* __restrict__ wt)
{
    int idx = blockIdx.x * 256 + threadIdx.x;     // output-ordered: ((p*128+oc)*256+ic)
    if (idx >= 81 * 128 * 256) return;
    int ic = idx & 255;
    int t  = idx >> 8;
    int oc = t & 127;
    int p  = t >> 7;
    wt[idx] = f2bf(w[(p * 256 + ic) * 128 + oc]);
}

// ---------------- conv2 implicit GEMM, bf16 MFMA 16x16x32, B in registers
// block: 64 M(ox) x 128 N(oc), 256 thr / 4 waves; wave w owns oc slice [32w,32w+32)
// A (x row, 135 cols) staged in LDS per (ky, ic-half), XOR-swizzled; B loaded
// global->reg per K chunk (each B fragment consumed by exactly one wave).
__global__ __launch_bounds__(256) void conv2_mfma_kernel(
    const unsigned short* __restrict__ x1bf,   // [2,242,242,256] bf16
    const unsigned short* __restrict__ w2t,    // [81,128,256] bf16
    const float* __restrict__ bias,
    float* __restrict__ out)                   // [2,117,117,128] fp32
{
    const int bx   = blockIdx.x;               // 0,1: ox tile of 64
    const int oy   = blockIdx.y;
    const int b    = blockIdx.z;
    const int tid  = threadIdx.x;
    const int wave = tid >> 6;
    const int lane = tid & 63;
    const int li   = lane & 15;
    const int quad = lane >> 4;
    const int wn   = wave * 32;
    const int ox0  = bx * 64;

    // A: [col 0..135) x [128 ic half], per col 16 chunks of 8 bf16, chunk XOR-swizzled
    __shared__ __align__(16) unsigned short As[135 * 128];   // 34,560 B

    f32x4 acc[4][2];
#pragma unroll
    for (int mt = 0; mt < 4; ++mt) {
        acc[mt][0] = (f32x4){0.f, 0.f, 0.f, 0.f};
        acc[mt][1] = (f32x4){0.f, 0.f, 0.f, 0.f};
    }

    const int n0 = wn + li;          // nt=0 oc
    const int n1 = wn + 16 + li;     // nt=1 oc
    const size_t bofs0 = (size_t)n0 * 256 + quad * 8;
    const size_t bofs1 = (size_t)n1 * 256 + quad * 8;

    for (int ky = 0; ky < 9; ++ky) {
        const int iy = 2 * oy + ky;                          // <= 240, in-bounds
        const unsigned short* xrow =
            x1bf + ((size_t)(b * 242 + iy) * 242 + 2 * ox0) * 256;

        for (int hq = 0; hq < 2; ++hq) {                     // ic half
            __syncthreads();                                 // prior As readers done
            // stage A half: 135 cols x 16 chunks of 16 B, swizzled source
            for (int it = 0; it < 9; ++it) {
                int ct = it * 256 + tid;
                if (ct < 135 * 16) {
                    int col = ct >> 4;
                    int cc  = ct & 15;
                    int src = cc ^ ((col >> 1) & 7);
                    *(short8*)&As[ct * 8] =
                        *(const short8*)&xrow[col * 256 + hq * 128 + src * 8];
                }
            }
            __syncthreads();

            const size_t bo0 = bofs0 + hq * 128;
            const size_t bo1 = bofs1 + hq * 128;

            for (int kx = 0; kx < 9; ++kx) {
                const unsigned short* wp = w2t + ((size_t)(ky * 9 + kx) << 15);
                const int colbase = (li << 1) + kx;
                const int sw = (li + (kx >> 1)) & 7;
                const unsigned short* abase = As + colbase * 128;
#pragma unroll
                for (int kc = 0; kc < 4; ++kc) {             // 32-ic MFMA chunks
                    bf16x8 b0 = *(const bf16x8*)&wp[bo0 + kc * 32];
                    bf16x8 b1 = *(const bf16x8*)&wp[bo1 + kc * 32];
                    const int chs = ((kc << 2) + quad) ^ sw;
#pragma unroll
                    for (int mt = 0; mt < 4; ++mt) {
                        bf16x8 a = *(const bf16x8*)&abase[mt * 4096 + chs * 8];
                        acc[mt][0] = __builtin_amdgcn_mfma_f32_16x16x32_bf16(a, b0, acc[mt][0], 0, 0, 0);
                        acc[mt][1] = __builtin_amdgcn_mfma_f32_16x16x32_bf16(a, b1, acc[mt][1], 0, 0, 0);
                    }
                }
            }
        }
    }

    // epilogue: C/D layout col(N)=lane&15, row(M)=quad*4+reg
    const float bv0 = bias[n0];
    const float bv1 = bias[n1];
#pragma unroll
    for (int mt = 0; mt < 4; ++mt) {
#pragma unroll
        for (int r = 0; r < 4; ++r) {
            const int m  = mt * 16 + quad * 4 + r;
            const int ox = ox0 + m;
            if (ox < 117) {
                float* op = &out[((size_t)(b * 117 + oy) * 117 + ox) * 128];
                op[n0] = acc[mt][0][r] + bv0;
                op[n1] = acc[mt][1][r] + bv1;
            }
        }
    }
}

// ---------------- squash over groups of 8 (in-place)
__global__ __launch_bounds__(256) void squash_u_kernel(float* data, int n_groups)
{
    int i = blockIdx.x * 256 + threadIdx.x;
    if (i >= n_groups) return;
    float4* p = (float4*)(data + (size_t)i * 8);
    float4 a = p[0], c = p[1];
    float sq = a.x * a.x + a.y * a.y + a.z * a.z + a.w * a.w
             + c.x * c.x + c.y * c.y + c.z * c.z + c.w * c.w;
    float scale = (sq / (1.f + sq)) * rsqrtf(sq + 1e-7f);
    p[0] = make_float4(a.x * scale, a.y * scale, a.z * scale, a.w * scale);
    p[1] = make_float4(c.x * scale, c.y * scale, c.z * scale, c.w * scale);
}

// ---------------- u_hat[b,j,i,o] = sum_d W[j,i,o,d] * u[b,i,d]
__global__ __launch_bounds__(256) void uhat_kernel(
    const float* __restrict__ W, const float* __restrict__ u,
    float* __restrict__ uhat)
{
    int idx = blockIdx.x * 256 + threadIdx.x;   // idx = j*N + i
    if (idx >= J_CAPS * N_CAPS) return;
    int j = idx / N_CAPS;
    int i = idx - j * N_CAPS;

    const float4* wp = (const float4*)(W + (size_t)idx * 64);
    const float4* u0 = (const float4*)(u + (size_t)i * 8);
    const float4* u1 = (const float4*)(u + ((size_t)N_CAPS + i) * 8);
    float4 u0a = u0[0], u0b = u0[1];
    float4 u1a = u1[0], u1b = u1[1];

    float o0[8], o1[8];
#pragma unroll
    for (int o = 0; o < 8; ++o) {
        float4 wa = wp[2 * o], wb = wp[2 * o + 1];
        o0[o] = wa.x * u0a.x + wa.y * u0a.y + wa.z * u0a.z + wa.w * u0a.w
              + wb.x * u0b.x + wb.y * u0b.y + wb.z * u0b.z + wb.w * u0b.w;
        o1[o] = wa.x * u1a.x + wa.y * u1a.y + wa.z * u1a.z + wa.w * u1a.w
              + wb.x * u1b.x + wb.y * u1b.y + wb.z * u1b.z + wb.w * u1b.w;
    }
    float4* d0 = (float4*)(uhat + ((size_t)(0 * J_CAPS + j) * N_CAPS + i) * 8);
    float4* d1 = (float4*)(uhat + ((size_t)(1 * J_CAPS + j) * N_CAPS + i) * 8);
    d0[0] = make_float4(o0[0], o0[1], o0[2], o0[3]);
    d0[1] = make_float4(o0[4], o0[5], o0[6], o0[7]);
    d1[0] = make_float4(o1[0], o1[1], o1[2], o1[3]);
    d1[1] = make_float4(o1[4], o1[5], o1[6], o1[7]);
}

// ---------------- fused routing iteration (MODE 0/1/2)
template <int MODE>
__global__ __launch_bounds__(256) void routing_kernel(
    const float* __restrict__ uhat, const float* __restrict__ vprev,
    const float* __restrict__ b_in, float* __restrict__ b_out,
    float* __restrict__ s)
{
    const int bb = blockIdx.y;
    __shared__ float vsh[64];
    __shared__ float ssh[64];
    if (threadIdx.x < 64) {
        ssh[threadIdx.x] = 0.f;
        vsh[threadIdx.x] = (MODE > 0) ? vprev[bb * 64 + threadIdx.x] : 0.f;
    }
    __syncthreads();

    float acc[64];
#pragma unroll
    for (int k = 0; k < 64; ++k) acc[k] = 0.f;

    const float* ub = uhat + (size_t)bb * J_CAPS * (size_t)N_CAPS * 8;
    for (int i = blockIdx.x * 256 + threadIdx.x; i < N_CAPS; i += gridDim.x * 256) {
        float uh[64];
#pragma unroll
        for (int j = 0; j < 8; ++j) {
            const float* p = ub + ((size_t)j * N_CAPS + i) * 8;
            float4 x0 = *(const float4*)p;
            float4 x1 = *(const float4*)(p + 4);
            uh[j * 8 + 0] = x0.x; uh[j * 8 + 1] = x0.y;
            uh[j * 8 + 2] = x0.z; uh[j * 8 + 3] = x0.w;
            uh[j * 8 + 4] = x1.x; uh[j * 8 + 5] = x1.y;
            uh[j * 8 + 6] = x1.z; uh[j * 8 + 7] = x1.w;
        }
        float c[8];
        if (MODE == 0) {
#pragma unroll
            for (int j = 0; j < 8; ++j) c[j] = 0.125f;
        } else {
            float bj[8];
#pragma unroll
            for (int j = 0; j < 8; ++j) {
                float d = 0.f;
#pragma unroll
                for (int o = 0; o < 8; ++o) d += vsh[j * 8 + o] * uh[j * 8 + o];
                bj[j] = d;
            }
            if (MODE == 2) {
#pragma unroll
                for (int j = 0; j < 8; ++j)
                    bj[j] += b_in[((size_t)bb * 8 + j) * N_CAPS + i];
            } else {
#pragma unroll
                for (int j = 0; j < 8; ++j)
                    b_out[((size_t)bb * 8 + j) * N_CAPS + i] = bj[j];
            }
            float m = bj[0];
#pragma unroll
            for (int j = 1; j < 8; ++j) m = fmaxf(m, bj[j]);
            float se = 0.f;
#pragma unroll
            for (int j = 0; j < 8; ++j) { c[j] = __expf(bj[j] - m); se += c[j]; }
            float inv = 1.f / se;
#pragma unroll
            for (int j = 0; j < 8; ++j) c[j] *= inv;
        }
#pragma unroll
        for (int k = 0; k < 64; ++k) acc[k] += c[k >> 3] * uh[k];
    }

#pragma unroll
    for (int k = 0; k < 64; ++k) {
        float v = acc[k];
        for (int off = 32; off > 0; off >>= 1)
            v += __shfl_down(v, off, 64);
        if ((threadIdx.x & 63) == 0) atomicAdd(&ssh[k], v);
    }
    __syncthreads();
    if (threadIdx.x < 64) atomicAdd(&s[bb * 64 + threadIdx.x], ssh[threadIdx.x]);
}

// ---------------- squash of s -> v
__global__ void squash_v_kernel(const float* __restrict__ s, float* __restrict__ v)
{
    int t = threadIdx.x;
    if (t >= 16) return;
    const float4* p = (const float4*)(s + t * 8);
    float4 a = p[0], c = p[1];
    float sq = a.x * a.x + a.y * a.y + a.z * a.z + a.w * a.w
             + c.x * c.x + c.y * c.y + c.z * c.z + c.w * c.w;
    float scale = (sq / (1.f + sq)) * rsqrtf(sq + 1e-7f);
    float4* d = (float4*)(v + t * 8);
    d[0] = make_float4(a.x * scale, a.y * scale, a.z * scale, a.w * scale);
    d[1] = make_float4(c.x * scale, c.y * scale, c.z * scale, c.w * scale);
}

__global__ void zero_kernel(float* p, int n)
{
    int i = blockIdx.x * 256 + threadIdx.x;
    if (i < n) p[i] = 0.f;
}

extern "C" void kernel_launch(void* const* d_in, const int* in_sizes, int n_in,
                              void* d_out, int out_size, void* d_ws, size_t ws_size,
                              hipStream_t stream)
{
    const float* in = (const float*)d_in[0];
    const float* w1 = (const float*)d_in[1];
    const float* b1 = (const float*)d_in[2];
    const float* w2 = (const float*)d_in[3];
    const float* b2 = (const float*)d_in[4];
    const float* Wc = (const float*)d_in[5];
    float* out = (float*)d_out;
    char* wsb  = (char*)d_ws;

    // workspace layout (bytes):
    //  [0, 112,140,288):  uhat fp32 [2,8,219024,8]; aliased by x1bf bf16 (dead before uhat)
    //  [112,140,288):     pc fp32  (14,017,536 B)
    //  [126,157,824):     blog fp32 (14,017,536 B)
    //  [140,175,360):     w2t bf16 (5,308,416 B)
    //  [145,483,776):     sbuf (512 B); [145,484,288): vbuf (512 B)
    float*          uhat = (float*)wsb;
    unsigned short* x1bf = (unsigned short*)wsb;
    float*          pc   = (float*)(wsb + 112140288);
    float*          blog = (float*)(wsb + 126157824);
    unsigned short* w2t  = (unsigned short*)(wsb + 140175360);
    float*          sbuf = (float*)(wsb + 145483776);
    float*          vbuf = (float*)(wsb + 145484288);

    w2_convert_kernel<<<(81 * 128 * 256 + 255) / 256, 256, 0, stream>>>(w2, w2t);
    conv1_kernel<<<dim3(16, 242, 2), 256, 0, stream>>>(in, w1, b1, x1bf);
    conv2_mfma_kernel<<<dim3(2, 117, 2), 256, 0, stream>>>(x1bf, w2t, b2, pc);
    squash_u_kernel<<<(2 * N_CAPS + 255) / 256, 256, 0, stream>>>(pc, 2 * N_CAPS);
    uhat_kernel<<<(J_CAPS * N_CAPS + 255) / 256, 256, 0, stream>>>(Wc, pc, uhat);

    zero_kernel<<<1, 128, 0, stream>>>(sbuf, 128);
    routing_kernel<0><<<dim3(256, 2), 256, 0, stream>>>(uhat, nullptr, nullptr, nullptr, sbuf);
    squash_v_kernel<<<1, 64, 0, stream>>>(sbuf, vbuf);

    zero_kernel<<<1, 128, 0, stream>>>(sbuf, 128);
    routing_kernel<1><<<dim3(256, 2), 256, 0, stream>>>(uhat, vbuf, nullptr, blog, sbuf);
    squash_v_kernel<<<1, 64, 0, stream>>>(sbuf, vbuf);

    zero_kernel<<<1, 128, 0, stream>>>(sbuf, 128);
    routing_kernel<2><<<dim3(256, 2), 256, 0, stream>>>(uhat, vbuf, blog, nullptr, sbuf);
    squash_v_kernel<<<1, 64, 0, stream>>>(sbuf, out);
}